// Round 2
// baseline (3838.519 us; speedup 1.0000x reference)
//
#include <hip/hip_runtime.h>
#include <hip/hip_bf16.h>

typedef unsigned int  u32;
typedef unsigned short u16;

#define B_ 64
#define N_ 2048
#define I_ 16
#define J_ 32
#define K_ 32
#define BJK (B_*J_*K_)   // 65536

__device__ __forceinline__ float bflo(u32 u){ return __uint_as_float(u << 16); }
__device__ __forceinline__ float bfhi(u32 u){ return __uint_as_float(u & 0xffff0000u); }

// ---- dtype sniffer ------------------------------------------------------
// fp32 data viewed as u16[]: even indices are random low-mantissa halves ->
// frequently decode (as bf16) with exponent >= 0x90 (|v| >= 2^17).
// Real bf16 data here: |X| <~ 6 (exp <= 0x82), |W| <~ 0.4 (exp <= 0x7E).
// flags[0]=1 iff X is fp32, flags[1]=1 iff W is fp32.
__global__ __launch_bounds__(256) void detect_dtype(const u16* __restrict__ X,
                                                    const u16* __restrict__ W,
                                                    int* __restrict__ flags)
{
  __shared__ int sx, sw;
  if (threadIdx.x == 0){ sx = 0; sw = 0; }
  __syncthreads();
  int bx = 0, bw = 0;
  for (int i = threadIdx.x; i < 8192; i += 256){
    int ex = (X[2*i] >> 7) & 0xFF;
    int ew = (W[2*i] >> 7) & 0xFF;
    if (ex >= 0x90) bx = 1;
    if (ew >= 0x90) bw = 1;
  }
  if (bx) atomicOr(&sx, 1);
  if (bw) atomicOr(&sw, 1);
  __syncthreads();
  if (threadIdx.x == 0){ flags[0] = sx; flags[1] = sw; }
}

// ---- main pass ----------------------------------------------------------
// Recompute u_hat[b,j,n,k] on the fly; accumulate s[b,j,k] = sum_n c*u_hat
// into per-nblk partials. R==0: c = 1/J. R>=1: c = softmax_j(sum_k o*u_hat),
// where o is out0 (R==1) or out0+out1 (R==2) -- logits are linear in outs.
// 4 waves/block share n (W L1 reuse); wave handles 2 b's.
// lane -> j = lane>>1, k-half = (lane&1)*16.
template<int R, bool WF32>
__device__ __forceinline__ void pass_body(
    const void* __restrict__ Xv, const void* __restrict__ Wv, bool xf32,
    const float* __restrict__ o, float* __restrict__ s_part,
    int nb, int nchunk, int bg, int w, int lane)
{
  const int j  = lane >> 1;
  const int kh = (lane & 1) << 4;
  const int b0 = bg*8 + w*2;
  const int b1 = b0 + 1;

  float o0[16], o1[16];
  if constexpr (R >= 1) {
    const float4* p0 = (const float4*)(o + ((b0*J_ + j)*K_ + kh));
    const float4* p1 = (const float4*)(o + ((b1*J_ + j)*K_ + kh));
    #pragma unroll
    for (int q=0;q<4;q++){
      float4 v0 = p0[q]; o0[4*q+0]=v0.x; o0[4*q+1]=v0.y; o0[4*q+2]=v0.z; o0[4*q+3]=v0.w;
      float4 v1 = p1[q]; o1[4*q+0]=v1.x; o1[4*q+1]=v1.y; o1[4*q+2]=v1.z; o1[4*q+3]=v1.w;
    }
  }

  float s0[16], s1[16];
  #pragma unroll
  for (int kk=0;kk<16;kk++){ s0[kk]=0.f; s1[kk]=0.f; }

  const int n_begin = nb * nchunk;
  int n_end = n_begin + nchunk; if (n_end > N_) n_end = N_;

  const size_t wj = (size_t)j * N_ * K_ * I_;   // element offset (u16 or f32)

  for (int n = n_begin; n < n_end; ++n) {
    // ---- stage x[b,n,0..15] ----
    float x0[16], x1[16];
    if (xf32) {
      const float4* xp0 = (const float4*)((const float*)Xv + ((size_t)b0*N_ + n)*I_);
      const float4* xp1 = (const float4*)((const float*)Xv + ((size_t)b1*N_ + n)*I_);
      #pragma unroll
      for (int q=0;q<4;q++){
        float4 v0 = xp0[q]; x0[4*q]=v0.x; x0[4*q+1]=v0.y; x0[4*q+2]=v0.z; x0[4*q+3]=v0.w;
        float4 v1 = xp1[q]; x1[4*q]=v1.x; x1[4*q+1]=v1.y; x1[4*q+2]=v1.z; x1[4*q+3]=v1.w;
      }
    } else {
      const uint4* xp0 = (const uint4*)((const u16*)Xv + ((size_t)b0*N_ + n)*I_);
      const uint4* xp1 = (const uint4*)((const u16*)Xv + ((size_t)b1*N_ + n)*I_);
      uint4 a = xp0[0], b = xp0[1];
      x0[0]=bflo(a.x); x0[1]=bfhi(a.x); x0[2]=bflo(a.y); x0[3]=bfhi(a.y);
      x0[4]=bflo(a.z); x0[5]=bfhi(a.z); x0[6]=bflo(a.w); x0[7]=bfhi(a.w);
      x0[8]=bflo(b.x); x0[9]=bfhi(b.x); x0[10]=bflo(b.y); x0[11]=bfhi(b.y);
      x0[12]=bflo(b.z); x0[13]=bfhi(b.z); x0[14]=bflo(b.w); x0[15]=bfhi(b.w);
      uint4 c = xp1[0], d = xp1[1];
      x1[0]=bflo(c.x); x1[1]=bfhi(c.x); x1[2]=bflo(c.y); x1[3]=bfhi(c.y);
      x1[4]=bflo(c.z); x1[5]=bfhi(c.z); x1[6]=bflo(c.w); x1[7]=bfhi(c.w);
      x1[8]=bflo(d.x); x1[9]=bfhi(d.x); x1[10]=bflo(d.y); x1[11]=bfhi(d.y);
      x1[12]=bflo(d.z); x1[13]=bfhi(d.z); x1[14]=bflo(d.w); x1[15]=bfhi(d.w);
    }

    // ---- u_hat for (b-pair, j, k-half, n): 16 k's x 16 i MACs ----
    float u0[16], u1[16];
    const uint4*  wrow_b = (const uint4*) ((const u16*)Wv   + wj + ((size_t)n*K_ + kh)*I_);
    const float4* wrow_f = (const float4*)((const float*)Wv + wj + ((size_t)n*K_ + kh)*I_);
    #pragma unroll
    for (int kk=0;kk<16;kk++){
      float wv[16];
      if constexpr (WF32) {
        #pragma unroll
        for (int q=0;q<4;q++){
          float4 t = wrow_f[kk*4+q];
          wv[4*q]=t.x; wv[4*q+1]=t.y; wv[4*q+2]=t.z; wv[4*q+3]=t.w;
        }
      } else {
        uint4 wa = wrow_b[kk*2+0];
        uint4 wb = wrow_b[kk*2+1];
        wv[0]=bflo(wa.x); wv[1]=bfhi(wa.x); wv[2]=bflo(wa.y); wv[3]=bfhi(wa.y);
        wv[4]=bflo(wa.z); wv[5]=bfhi(wa.z); wv[6]=bflo(wa.w); wv[7]=bfhi(wa.w);
        wv[8]=bflo(wb.x); wv[9]=bfhi(wb.x); wv[10]=bflo(wb.y); wv[11]=bfhi(wb.y);
        wv[12]=bflo(wb.z); wv[13]=bfhi(wb.z); wv[14]=bflo(wb.w); wv[15]=bfhi(wb.w);
      }
      float a0=0.f, a1=0.f;
      #pragma unroll
      for (int i=0;i<16;i++){ a0 += wv[i]*x0[i]; a1 += wv[i]*x1[i]; }
      u0[kk]=a0; u1[kk]=a1;
    }

    if constexpr (R == 0) {
      const float cc = 1.0f/(float)J_;
      #pragma unroll
      for (int kk=0;kk<16;kk++){ s0[kk] += cc*u0[kk]; s1[kk] += cc*u1[kk]; }
    } else {
      float d0=0.f, d1=0.f;
      #pragma unroll
      for (int kk=0;kk<16;kk++){ d0 += o0[kk]*u0[kk]; d1 += o1[kk]*u1[kk]; }
      d0 += __shfl_xor(d0, 1, 64);   // combine the two k-halves
      d1 += __shfl_xor(d1, 1, 64);
      float m0=d0, m1=d1;            // softmax over 32 j's (lane bits 1..5)
      m0 = fmaxf(m0, __shfl_xor(m0, 2,64)); m1 = fmaxf(m1, __shfl_xor(m1, 2,64));
      m0 = fmaxf(m0, __shfl_xor(m0, 4,64)); m1 = fmaxf(m1, __shfl_xor(m1, 4,64));
      m0 = fmaxf(m0, __shfl_xor(m0, 8,64)); m1 = fmaxf(m1, __shfl_xor(m1, 8,64));
      m0 = fmaxf(m0, __shfl_xor(m0,16,64)); m1 = fmaxf(m1, __shfl_xor(m1,16,64));
      m0 = fmaxf(m0, __shfl_xor(m0,32,64)); m1 = fmaxf(m1, __shfl_xor(m1,32,64));
      float e0 = __expf(d0-m0), e1 = __expf(d1-m1);
      float t0 = e0, t1 = e1;
      t0 += __shfl_xor(t0, 2,64); t1 += __shfl_xor(t1, 2,64);
      t0 += __shfl_xor(t0, 4,64); t1 += __shfl_xor(t1, 4,64);
      t0 += __shfl_xor(t0, 8,64); t1 += __shfl_xor(t1, 8,64);
      t0 += __shfl_xor(t0,16,64); t1 += __shfl_xor(t1,16,64);
      t0 += __shfl_xor(t0,32,64); t1 += __shfl_xor(t1,32,64);
      float c0 = e0/t0, c1 = e1/t1;
      #pragma unroll
      for (int kk=0;kk<16;kk++){ s0[kk] += c0*u0[kk]; s1[kk] += c1*u1[kk]; }
    }
    __syncthreads();  // keep the 4 waves on the same n for L1 W-reuse
  }

  float* sp = s_part + (size_t)nb*BJK;
  float4* q0 = (float4*)(sp + ((b0*J_ + j)*K_ + kh));
  float4* q1 = (float4*)(sp + ((b1*J_ + j)*K_ + kh));
  #pragma unroll
  for (int q=0;q<4;q++){
    q0[q] = make_float4(s0[4*q+0],s0[4*q+1],s0[4*q+2],s0[4*q+3]);
    q1[q] = make_float4(s1[4*q+0],s1[4*q+1],s1[4*q+2],s1[4*q+3]);
  }
}

template<int R>
__global__ __launch_bounds__(256) void pass_kernel(
    const void* __restrict__ X, const void* __restrict__ Wv,
    const int* __restrict__ flags,
    const float* __restrict__ o, float* __restrict__ s_part, int nchunk)
{
  const int bg   = blockIdx.x & 7;
  const int nb   = blockIdx.x >> 3;
  const int w    = threadIdx.x >> 6;
  const int lane = threadIdx.x & 63;
  const bool xf  = flags[0] != 0;
  if (flags[1]) pass_body<R,true >(X, Wv, xf, o, s_part, nb, nchunk, bg, w, lane);
  else          pass_body<R,false>(X, Wv, xf, o, s_part, nb, nchunk, bg, w, lane);
}

// Sum partials over nblk, squash along k (32 lanes = one (b,j) row).
// R==0: out0 (fp32 ws). R==1: osum = out0 + squash(s1). R==2: final to d_out.
template<int R>
__global__ __launch_bounds__(256) void reduce_squash(
    const float* __restrict__ s_part, int nblk_count,
    const int* __restrict__ flags,
    const float* __restrict__ add_prev, float* __restrict__ out_f,
    void* __restrict__ d_out)
{
  const int idx = blockIdx.x*256 + threadIdx.x;   // [0, 65536)
  float sum = 0.f;
  for (int p=0; p<nblk_count; ++p) sum += s_part[(size_t)p*BJK + idx];
  float sq = sum*sum;
  sq += __shfl_xor(sq, 1,64);
  sq += __shfl_xor(sq, 2,64);
  sq += __shfl_xor(sq, 4,64);
  sq += __shfl_xor(sq, 8,64);
  sq += __shfl_xor(sq,16,64);
  const float scale = sq / (1.0f + sq) / sqrtf(sq + 1e-7f);
  const float val = scale * sum;
  if constexpr (R == 0) out_f[idx] = val;
  if constexpr (R == 1) out_f[idx] = val + add_prev[idx];
  if constexpr (R == 2) {
    const bool f32out = (flags[0] != 0) && (flags[1] != 0);
    if (f32out) ((float*)d_out)[idx] = val;
    else        ((__hip_bfloat16*)d_out)[idx] = __float2bfloat16(val);
  }
}

extern "C" void kernel_launch(void* const* d_in, const int* in_sizes, int n_in,
                              void* d_out, int out_size, void* d_ws, size_t ws_size,
                              hipStream_t stream)
{
  const void* X  = d_in[0];   // [B][N][I]     (bf16 or fp32 -- sniffed)
  const void* Wm = d_in[1];   // [J][N][K][I]  (bf16 or fp32 -- sniffed)

  float* out0  = (float*)d_ws;            // BJK f32
  float* osum  = out0 + BJK;              // BJK f32
  int*   flags = (int*)(osum + BJK);      // 64 f32 slot reserved
  float* spart = (float*)(osum + BJK + 64);

  long avail = (long)(ws_size / 4) - (2L*BJK + 64);
  int nblk = (int)(avail / BJK);
  if (nblk > 128) nblk = 128;
  if (nblk < 1)   nblk = 1;
  const int nchunk = (N_ + nblk - 1) / nblk;

  dim3 grid(8*nblk), blk(256);
  dim3 rgrid(BJK/256), rblk(256);

  detect_dtype<<<1, 256, 0, stream>>>((const u16*)X, (const u16*)Wm, flags);

  pass_kernel<0><<<grid, blk, 0, stream>>>(X, Wm, flags, (const float*)nullptr, spart, nchunk);
  reduce_squash<0><<<rgrid, rblk, 0, stream>>>(spart, nblk, flags, (const float*)nullptr, out0, nullptr);

  pass_kernel<1><<<grid, blk, 0, stream>>>(X, Wm, flags, out0, spart, nchunk);
  reduce_squash<1><<<rgrid, rblk, 0, stream>>>(spart, nblk, flags, out0, osum, nullptr);

  pass_kernel<2><<<grid, blk, 0, stream>>>(X, Wm, flags, osum, spart, nchunk);
  reduce_squash<2><<<rgrid, rblk, 0, stream>>>(spart, nblk, flags, (const float*)nullptr, (float*)nullptr, d_out);
}

// Round 3
// 2958.055 us; speedup vs baseline: 1.2976x; 1.2976x over previous
//
#include <hip/hip_runtime.h>
#include <hip/hip_bf16.h>

typedef unsigned int  u32;
typedef unsigned short u16;

#define B_ 64
#define N_ 2048
#define I_ 16
#define J_ 32
#define K_ 32
#define BJK (B_*J_*K_)   // 65536
#define NCHUNKS 128
#define NCHUNK  (N_/NCHUNKS)   // 16

__device__ __forceinline__ float bflo(u32 u){ return __uint_as_float(u << 16); }
__device__ __forceinline__ float bfhi(u32 u){ return __uint_as_float(u & 0xffff0000u); }

// ---- dtype sniffer + zero s-accum --------------------------------------
// flags[0]=1 iff X is fp32, flags[1]=1 iff W is fp32 (see round-1 notes).
// All 64 blocks zero their slice of s_accum; block 0 also sniffs.
__global__ __launch_bounds__(256) void detect_zero(const u16* __restrict__ X,
                                                   const u16* __restrict__ W,
                                                   int* __restrict__ flags,
                                                   float* __restrict__ s_accum)
{
  float4* z = (float4*)s_accum;
  z[blockIdx.x*256 + threadIdx.x] = make_float4(0.f,0.f,0.f,0.f);  // 64*256*16B = 256KB

  if (blockIdx.x == 0) {
    __shared__ int sx, sw;
    if (threadIdx.x == 0){ sx = 0; sw = 0; }
    __syncthreads();
    int bx = 0, bw = 0;
    for (int i = threadIdx.x; i < 8192; i += 256){
      int ex = (X[2*i] >> 7) & 0xFF;
      int ew = (W[2*i] >> 7) & 0xFF;
      if (ex >= 0x90) bx = 1;
      if (ew >= 0x90) bw = 1;
    }
    if (bx) atomicOr(&sx, 1);
    if (bw) atomicOr(&sw, 1);
    __syncthreads();
    if (threadIdx.x == 0){ flags[0] = sx; flags[1] = sw; }
  }
}

// ---- main pass (inner logic identical to round 2) ----------------------
// Recompute u_hat[b,j,n,k] on the fly; accumulate s[b,j,k] = sum_n c*u_hat
// via atomicAdd into a single 256KB buffer. R==0: c = 1/J. R>=1:
// c = softmax_j(sum_k o*u_hat), o = out0 (R==1) or out0+out1 (R==2).
// 4 waves/block share n; wave handles 2 b's. lane -> j=lane>>1, kh=(lane&1)*16.
template<int R, bool WF32>
__device__ __forceinline__ void pass_body(
    const void* __restrict__ Xv, const void* __restrict__ Wv, bool xf32,
    const float* __restrict__ o, float* __restrict__ s_accum,
    int nb, int bg, int w, int lane)
{
  const int j  = lane >> 1;
  const int kh = (lane & 1) << 4;
  const int b0 = bg*8 + w*2;
  const int b1 = b0 + 1;

  float o0[16], o1[16];
  if constexpr (R >= 1) {
    const float4* p0 = (const float4*)(o + ((b0*J_ + j)*K_ + kh));
    const float4* p1 = (const float4*)(o + ((b1*J_ + j)*K_ + kh));
    #pragma unroll
    for (int q=0;q<4;q++){
      float4 v0 = p0[q]; o0[4*q+0]=v0.x; o0[4*q+1]=v0.y; o0[4*q+2]=v0.z; o0[4*q+3]=v0.w;
      float4 v1 = p1[q]; o1[4*q+0]=v1.x; o1[4*q+1]=v1.y; o1[4*q+2]=v1.z; o1[4*q+3]=v1.w;
    }
  }

  float s0[16], s1[16];
  #pragma unroll
  for (int kk=0;kk<16;kk++){ s0[kk]=0.f; s1[kk]=0.f; }

  const int n_begin = nb * NCHUNK;
  const int n_end   = n_begin + NCHUNK;

  const size_t wj = (size_t)j * N_ * K_ * I_;   // element offset

  for (int n = n_begin; n < n_end; ++n) {
    // ---- stage x[b,n,0..15] ----
    float x0[16], x1[16];
    if (xf32) {
      const float4* xp0 = (const float4*)((const float*)Xv + ((size_t)b0*N_ + n)*I_);
      const float4* xp1 = (const float4*)((const float*)Xv + ((size_t)b1*N_ + n)*I_);
      #pragma unroll
      for (int q=0;q<4;q++){
        float4 v0 = xp0[q]; x0[4*q]=v0.x; x0[4*q+1]=v0.y; x0[4*q+2]=v0.z; x0[4*q+3]=v0.w;
        float4 v1 = xp1[q]; x1[4*q]=v1.x; x1[4*q+1]=v1.y; x1[4*q+2]=v1.z; x1[4*q+3]=v1.w;
      }
    } else {
      const uint4* xp0 = (const uint4*)((const u16*)Xv + ((size_t)b0*N_ + n)*I_);
      const uint4* xp1 = (const uint4*)((const u16*)Xv + ((size_t)b1*N_ + n)*I_);
      uint4 a = xp0[0], b = xp0[1];
      x0[0]=bflo(a.x); x0[1]=bfhi(a.x); x0[2]=bflo(a.y); x0[3]=bfhi(a.y);
      x0[4]=bflo(a.z); x0[5]=bfhi(a.z); x0[6]=bflo(a.w); x0[7]=bfhi(a.w);
      x0[8]=bflo(b.x); x0[9]=bfhi(b.x); x0[10]=bflo(b.y); x0[11]=bfhi(b.y);
      x0[12]=bflo(b.z); x0[13]=bfhi(b.z); x0[14]=bflo(b.w); x0[15]=bfhi(b.w);
      uint4 c = xp1[0], d = xp1[1];
      x1[0]=bflo(c.x); x1[1]=bfhi(c.x); x1[2]=bflo(c.y); x1[3]=bfhi(c.y);
      x1[4]=bflo(c.z); x1[5]=bfhi(c.z); x1[6]=bflo(c.w); x1[7]=bfhi(c.w);
      x1[8]=bflo(d.x); x1[9]=bfhi(d.x); x1[10]=bflo(d.y); x1[11]=bfhi(d.y);
      x1[12]=bflo(d.z); x1[13]=bfhi(d.z); x1[14]=bflo(d.w); x1[15]=bfhi(d.w);
    }

    // ---- u_hat for (b-pair, j, k-half, n): 16 k's x 16 i MACs ----
    float u0[16], u1[16];
    const uint4*  wrow_b = (const uint4*) ((const u16*)Wv   + wj + ((size_t)n*K_ + kh)*I_);
    const float4* wrow_f = (const float4*)((const float*)Wv + wj + ((size_t)n*K_ + kh)*I_);
    #pragma unroll
    for (int kk=0;kk<16;kk++){
      float wv[16];
      if constexpr (WF32) {
        #pragma unroll
        for (int q=0;q<4;q++){
          float4 t = wrow_f[kk*4+q];
          wv[4*q]=t.x; wv[4*q+1]=t.y; wv[4*q+2]=t.z; wv[4*q+3]=t.w;
        }
      } else {
        uint4 wa = wrow_b[kk*2+0];
        uint4 wb = wrow_b[kk*2+1];
        wv[0]=bflo(wa.x); wv[1]=bfhi(wa.x); wv[2]=bflo(wa.y); wv[3]=bfhi(wa.y);
        wv[4]=bflo(wa.z); wv[5]=bfhi(wa.z); wv[6]=bflo(wa.w); wv[7]=bfhi(wa.w);
        wv[8]=bflo(wb.x); wv[9]=bfhi(wb.x); wv[10]=bflo(wb.y); wv[11]=bfhi(wb.y);
        wv[12]=bflo(wb.z); wv[13]=bfhi(wb.z); wv[14]=bflo(wb.w); wv[15]=bfhi(wb.w);
      }
      float a0=0.f, a1=0.f;
      #pragma unroll
      for (int i=0;i<16;i++){ a0 += wv[i]*x0[i]; a1 += wv[i]*x1[i]; }
      u0[kk]=a0; u1[kk]=a1;
    }

    if constexpr (R == 0) {
      const float cc = 1.0f/(float)J_;
      #pragma unroll
      for (int kk=0;kk<16;kk++){ s0[kk] += cc*u0[kk]; s1[kk] += cc*u1[kk]; }
    } else {
      float d0=0.f, d1=0.f;
      #pragma unroll
      for (int kk=0;kk<16;kk++){ d0 += o0[kk]*u0[kk]; d1 += o1[kk]*u1[kk]; }
      d0 += __shfl_xor(d0, 1, 64);   // combine the two k-halves
      d1 += __shfl_xor(d1, 1, 64);
      float m0=d0, m1=d1;            // softmax over 32 j's (lane bits 1..5)
      m0 = fmaxf(m0, __shfl_xor(m0, 2,64)); m1 = fmaxf(m1, __shfl_xor(m1, 2,64));
      m0 = fmaxf(m0, __shfl_xor(m0, 4,64)); m1 = fmaxf(m1, __shfl_xor(m1, 4,64));
      m0 = fmaxf(m0, __shfl_xor(m0, 8,64)); m1 = fmaxf(m1, __shfl_xor(m1, 8,64));
      m0 = fmaxf(m0, __shfl_xor(m0,16,64)); m1 = fmaxf(m1, __shfl_xor(m1,16,64));
      m0 = fmaxf(m0, __shfl_xor(m0,32,64)); m1 = fmaxf(m1, __shfl_xor(m1,32,64));
      float e0 = __expf(d0-m0), e1 = __expf(d1-m1);
      float t0 = e0, t1 = e1;
      t0 += __shfl_xor(t0, 2,64); t1 += __shfl_xor(t1, 2,64);
      t0 += __shfl_xor(t0, 4,64); t1 += __shfl_xor(t1, 4,64);
      t0 += __shfl_xor(t0, 8,64); t1 += __shfl_xor(t1, 8,64);
      t0 += __shfl_xor(t0,16,64); t1 += __shfl_xor(t1,16,64);
      t0 += __shfl_xor(t0,32,64); t1 += __shfl_xor(t1,32,64);
      float c0 = e0/t0, c1 = e1/t1;
      #pragma unroll
      for (int kk=0;kk<16;kk++){ s0[kk] += c0*u0[kk]; s1[kk] += c1*u1[kk]; }
    }
    __syncthreads();  // keep the 4 waves on the same n for L1 W-reuse
  }

  // atomic accumulation (64 n-chunk writers per address, once per block)
  float* q0 = s_accum + ((b0*J_ + j)*K_ + kh);
  float* q1 = s_accum + ((b1*J_ + j)*K_ + kh);
  #pragma unroll
  for (int kk=0;kk<16;kk++){
    atomicAdd(q0 + kk, s0[kk]);
    atomicAdd(q1 + kk, s1[kk]);
  }
}

template<int R>
__global__ __launch_bounds__(256) void pass_kernel(
    const void* __restrict__ X, const void* __restrict__ Wv,
    const int* __restrict__ flags,
    const float* __restrict__ o, float* __restrict__ s_accum)
{
  const int bg   = blockIdx.x & 7;
  const int nb   = blockIdx.x >> 3;     // 0..127
  const int w    = threadIdx.x >> 6;
  const int lane = threadIdx.x & 63;
  const bool xf  = flags[0] != 0;
  if (flags[1]) pass_body<R,true >(X, Wv, xf, o, s_accum, nb, bg, w, lane);
  else          pass_body<R,false>(X, Wv, xf, o, s_accum, nb, bg, w, lane);
}

// Squash along k (32 lanes = one (b,j) row); re-zeros s_accum for next pass.
// R==0: out0 (fp32 ws). R==1: osum = out0 + squash(s). R==2: final to d_out.
template<int R>
__global__ __launch_bounds__(256) void reduce_squash(
    float* __restrict__ s_accum,
    const int* __restrict__ flags,
    const float* __restrict__ add_prev, float* __restrict__ out_f,
    void* __restrict__ d_out)
{
  const int idx = blockIdx.x*256 + threadIdx.x;   // [0, 65536)
  float sum = s_accum[idx];
  s_accum[idx] = 0.f;                             // re-zero for next pass
  float sq = sum*sum;
  sq += __shfl_xor(sq, 1,64);
  sq += __shfl_xor(sq, 2,64);
  sq += __shfl_xor(sq, 4,64);
  sq += __shfl_xor(sq, 8,64);
  sq += __shfl_xor(sq,16,64);
  const float scale = sq / (1.0f + sq) / sqrtf(sq + 1e-7f);
  const float val = scale * sum;
  if constexpr (R == 0) out_f[idx] = val;
  if constexpr (R == 1) out_f[idx] = val + add_prev[idx];
  if constexpr (R == 2) {
    const bool f32out = (flags[0] != 0) && (flags[1] != 0);
    if (f32out) ((float*)d_out)[idx] = val;
    else        ((__hip_bfloat16*)d_out)[idx] = __float2bfloat16(val);
  }
}

extern "C" void kernel_launch(void* const* d_in, const int* in_sizes, int n_in,
                              void* d_out, int out_size, void* d_ws, size_t ws_size,
                              hipStream_t stream)
{
  const void* X  = d_in[0];   // [B][N][I]     fp32 (sniffed)
  const void* Wm = d_in[1];   // [J][N][K][I]  fp32 (sniffed)

  float* sacc  = (float*)d_ws;            // BJK f32 (256 KB)
  float* out0  = sacc + BJK;              // BJK f32
  float* osum  = out0 + BJK;              // BJK f32
  int*   flags = (int*)(osum + BJK);      // 4 ints (64-slot pad)
  // total: 3*BJK*4 + 256 B = 786,688 B  (== round-2 proven minimum)

  dim3 grid(8*NCHUNKS), blk(256);         // 1024 blocks
  dim3 rgrid(BJK/256), rblk(256);

  detect_zero<<<64, 256, 0, stream>>>((const u16*)X, (const u16*)Wm, flags, sacc);

  pass_kernel<0><<<grid, blk, 0, stream>>>(X, Wm, flags, (const float*)nullptr, sacc);
  reduce_squash<0><<<rgrid, rblk, 0, stream>>>(sacc, flags, (const float*)nullptr, out0, nullptr);

  pass_kernel<1><<<grid, blk, 0, stream>>>(X, Wm, flags, out0, sacc);
  reduce_squash<1><<<rgrid, rblk, 0, stream>>>(sacc, flags, out0, osum, nullptr);

  pass_kernel<2><<<grid, blk, 0, stream>>>(X, Wm, flags, osum, sacc);
  reduce_squash<2><<<rgrid, rblk, 0, stream>>>(sacc, flags, (const float*)nullptr, (float*)nullptr, d_out);
}

// Round 4
// 1807.453 us; speedup vs baseline: 2.1237x; 1.6366x over previous
//
#include <hip/hip_runtime.h>
#include <hip/hip_bf16.h>

typedef unsigned int  u32;
typedef unsigned short u16;

#define B_ 64
#define N_ 2048
#define I_ 16
#define J_ 32
#define K_ 32
#define KI_ (K_*I_)        // 512
#define NI_ (N_*I_)        // 32768
#define BJK 65536

__device__ __forceinline__ float bf2f(u16 u){ return __uint_as_float(((u32)u)<<16); }
__device__ __forceinline__ float bflo(u32 u){ return __uint_as_float(u<<16); }
__device__ __forceinline__ float bfhi(u32 u){ return __uint_as_float(u & 0xffff0000u); }

// ---- dtype sniffer + zero s_accum (proven in rounds 2-3) ----------------
// flags[0]=1 iff X is fp32, flags[1]=1 iff W is fp32. Low u16 halves of fp32
// floats are random mantissa bits -> bf16-exponent>=0x90 appears w.h.p.
__global__ __launch_bounds__(256) void detect_zero(const u16* __restrict__ X,
                                                   const u16* __restrict__ W,
                                                   int* __restrict__ flags,
                                                   float* __restrict__ s_acc)
{
  float4* z = (float4*)s_acc;
  z[blockIdx.x*256 + threadIdx.x] = make_float4(0.f,0.f,0.f,0.f);  // 64*256*16B = 256KB

  if (blockIdx.x == 0) {
    __shared__ int sx, sw;
    if (threadIdx.x == 0){ sx = 0; sw = 0; }
    __syncthreads();
    int bx = 0, bw = 0;
    for (int i = threadIdx.x; i < 8192; i += 256){
      int ex = (X[2*i] >> 7) & 0xFF;
      int ew = (W[2*i] >> 7) & 0xFF;
      if (ex >= 0x90) bx = 1;
      if (ew >= 0x90) bw = 1;
    }
    if (bx) atomicOr(&sx, 1);
    if (bw) atomicOr(&sw, 1);
    __syncthreads();
    if (threadIdx.x == 0){ flags[0] = sx; flags[1] = sw; }
  }
}

// ---- X[b][ni] -> X_t[ni][b] (fp32 out), LDS-tiled, conflict-free --------
__global__ __launch_bounds__(256) void transpose_x(const void* __restrict__ Xv,
                                                   const int* __restrict__ flags,
                                                   float* __restrict__ X_t)
{
  __shared__ float tile[64][65];
  const int base = blockIdx.x * 64;          // ni tile base (512 blocks)
  const int lane = threadIdx.x & 63;
  const int w    = threadIdx.x >> 6;
  const bool xf32 = flags[0] != 0;
  #pragma unroll
  for (int rr=0; rr<16; ++rr){
    const int b = w*16 + rr;
    float v;
    if (xf32) v = ((const float*)Xv)[(size_t)b*NI_ + base + lane];
    else      v = bf2f(((const u16*)Xv)[(size_t)b*NI_ + base + lane]);
    tile[lane][b] = v;
  }
  __syncthreads();
  #pragma unroll
  for (int rr=0; rr<16; ++rr){
    const int ni = w*16 + rr;
    X_t[(size_t)(base+ni)*64 + lane] = tile[ni][lane];
  }
}

// ---- accum: s[b,j,k] += sum_n c[b,j,n] * u_hat[b,j,n,k] -----------------
// lane=b. W is wave-uniform -> scalar loads via readfirstlane'd offset.
// R==0: c = 1/32 (softmax of zeros). R==1: c from c_buf.
template<int R, bool WF32>
__device__ __forceinline__ void accum_body(
    const float* __restrict__ X_t, const void* __restrict__ Wv,
    const float* __restrict__ c_buf, float* __restrict__ s_acc, int n0)
{
  const int lane = threadIdx.x & 63;
  const int w    = threadIdx.x >> 6;
  const int ch   = blockIdx.x;      // chunk of 64 n
  const int j    = blockIdx.y;

  float s[K_];
  #pragma unroll
  for (int k=0;k<K_;++k) s[k]=0.f;

  #pragma unroll 1
  for (int t=0;t<16;++t){
    const int n = n0 + ch*64 + w*16 + t;
    const float* xp = X_t + (size_t)n*1024 + lane;
    float x[I_];
    #pragma unroll
    for (int i=0;i<I_;++i) x[i] = xp[i*64];
    float cc;
    if constexpr (R==0) cc = 1.0f/32.0f;
    else                cc = c_buf[((size_t)(n-n0)*J_ + j)*64 + lane];
    const int wb = __builtin_amdgcn_readfirstlane((j*N_ + n)*KI_);
    if constexpr (WF32){
      const float* wp = (const float*)Wv + wb;
      #pragma unroll
      for (int k=0;k<K_;++k){
        float u0=0.f,u1=0.f;
        #pragma unroll
        for (int i=0;i<I_;i+=2){ u0 += wp[k*I_+i]*x[i]; u1 += wp[k*I_+i+1]*x[i+1]; }
        s[k] += cc*(u0+u1);
      }
    } else {
      const u32* wp = (const u32*)((const u16*)Wv + wb);
      #pragma unroll
      for (int k=0;k<K_;++k){
        float u0=0.f,u1=0.f;
        #pragma unroll
        for (int ii=0;ii<8;++ii){ u32 ww = wp[k*8+ii]; u0 += bflo(ww)*x[2*ii]; u1 += bfhi(ww)*x[2*ii+1]; }
        s[k] += cc*(u0+u1);
      }
    }
  }

  #pragma unroll
  for (int k=0;k<K_;++k)
    atomicAdd(s_acc + (j*K_ + k)*64 + lane, s[k]);
}

template<int R>
__global__ __launch_bounds__(256) void accum_kernel(
    const float* __restrict__ X_t, const void* __restrict__ Wv,
    const int* __restrict__ flags, const float* __restrict__ c_buf,
    float* __restrict__ s_acc, int n0)
{
  if (flags[1]) accum_body<R,true >(X_t,Wv,c_buf,s_acc,n0);
  else          accum_body<R,false>(X_t,Wv,c_buf,s_acc,n0);
}

// ---- logits: c[n][j][b] = softmax_j( sum_k o[b,j,k] * u_hat[b,j,n,k] ) --
// lane=b owns all 32 j logits -> softmax entirely in-lane (no LDS/shuffles).
// Raw logits round-trip through c_buf (L1-hot) to avoid dynamic reg indexing.
template<bool WF32>
__device__ __forceinline__ void logits_body(
    const float* __restrict__ X_t, const void* __restrict__ Wv,
    const float* __restrict__ o_t, float* __restrict__ c_buf, int n0)
{
  const int lane = threadIdx.x & 63;
  const int w    = threadIdx.x >> 6;
  const int n    = n0 + blockIdx.x*4 + w;

  const float* xp = X_t + (size_t)n*1024 + lane;
  float x[I_];
  #pragma unroll
  for (int i=0;i<I_;++i) x[i] = xp[i*64];

  float* crow = c_buf + (size_t)(n-n0)*J_*64 + lane;
  const int nb = __builtin_amdgcn_readfirstlane(n*KI_);

  float m = -1e30f;
  #pragma unroll 1
  for (int j=0;j<J_;++j){
    float dj = 0.f;
    const float* op = o_t + j*(K_*64) + lane;
    if constexpr (WF32){
      const float* wp = (const float*)Wv + j*(N_*KI_) + nb;
      #pragma unroll
      for (int k=0;k<K_;++k){
        float u0=0.f,u1=0.f;
        #pragma unroll
        for (int i=0;i<I_;i+=2){ u0 += wp[k*I_+i]*x[i]; u1 += wp[k*I_+i+1]*x[i+1]; }
        dj += op[k*64]*(u0+u1);
      }
    } else {
      const u32* wp = (const u32*)((const u16*)Wv) + (size_t)j*(N_*KI_/2) + (nb>>1);
      #pragma unroll
      for (int k=0;k<K_;++k){
        float u0=0.f,u1=0.f;
        #pragma unroll
        for (int ii=0;ii<8;++ii){ u32 ww = wp[k*8+ii]; u0 += bflo(ww)*x[2*ii]; u1 += bfhi(ww)*x[2*ii+1]; }
        dj += op[k*64]*(u0+u1);
      }
    }
    crow[j*64] = dj;
    m = fmaxf(m, dj);
  }
  float tot = 0.f;
  #pragma unroll 1
  for (int j=0;j<J_;++j){ float e = __expf(crow[j*64]-m); crow[j*64]=e; tot+=e; }
  const float inv = 1.0f/tot;
  #pragma unroll 1
  for (int j=0;j<J_;++j) crow[j*64] *= inv;
}

__global__ __launch_bounds__(256) void logits_kernel(
    const float* __restrict__ X_t, const void* __restrict__ Wv,
    const int* __restrict__ flags, const float* __restrict__ o_t,
    float* __restrict__ c_buf, int n0)
{
  if (flags[1]) logits_body<true >(X_t,Wv,o_t,c_buf,n0);
  else          logits_body<false>(X_t,Wv,o_t,c_buf,n0);
}

// ---- squash + o_t maintenance + s_acc re-zero ---------------------------
// R==0: o_t = squash(s). R==1: o_t += squash(s). R==2: d_out[b][j][k].
template<int R>
__global__ __launch_bounds__(256) void squash_kernel(
    float* __restrict__ s_acc, float* __restrict__ o_t,
    const int* __restrict__ flags, void* __restrict__ d_out)
{
  const int lane = threadIdx.x & 63;
  const int w    = threadIdx.x >> 6;
  const int j    = blockIdx.x*4 + w;       // grid 8
  float v[K_]; float sq=0.f;
  #pragma unroll
  for (int k=0;k<K_;++k){ v[k] = s_acc[(j*K_+k)*64 + lane]; sq += v[k]*v[k]; }
  #pragma unroll
  for (int k=0;k<K_;++k) s_acc[(j*K_+k)*64 + lane] = 0.f;
  const float scale = sq/(1.f+sq)/sqrtf(sq+1e-7f);
  if constexpr (R==0){
    #pragma unroll
    for (int k=0;k<K_;++k) o_t[(j*K_+k)*64 + lane] = scale*v[k];
  } else if constexpr (R==1){
    #pragma unroll
    for (int k=0;k<K_;++k) o_t[(j*K_+k)*64 + lane] += scale*v[k];
  } else {
    const bool f32o = (flags[0]!=0) && (flags[1]!=0);
    if (f32o){
      float* po = (float*)d_out;
      #pragma unroll
      for (int k=0;k<K_;++k) po[lane*(J_*K_) + j*K_ + k] = scale*v[k];
    } else {
      __hip_bfloat16* po = (__hip_bfloat16*)d_out;
      #pragma unroll
      for (int k=0;k<K_;++k) po[lane*(J_*K_) + j*K_ + k] = __float2bfloat16(scale*v[k]);
    }
  }
}

extern "C" void kernel_launch(void* const* d_in, const int* in_sizes, int n_in,
                              void* d_out, int out_size, void* d_ws, size_t ws_size,
                              hipStream_t stream)
{
  const void* X  = d_in[0];   // [B][N][I]     (dtype sniffed)
  const void* Wm = d_in[1];   // [J][N][K][I]  (dtype sniffed)

  float* s_acc = (float*)d_ws;                 // 65536 f32 (256 KB)
  float* o_t   = s_acc + BJK;                  // 65536 f32 (accumulated outs, [j][k][b])
  int*   flags = (int*)(o_t + BJK);            // 64-float pad
  float* X_t   = (float*)(o_t + BJK + 64);     // 2,097,152 f32 (8 MB)
  float* c_buf = X_t + (size_t)N_*I_*B_;       // SL*2048 f32 (<=16 MB)

  // pick smallest power-of-two segment count whose c_buf fits ws
  const size_t fixed = (size_t)BJK*2 + 64 + (size_t)N_*I_*B_;
  const size_t avail = (ws_size/4 > fixed) ? (ws_size/4 - fixed) : 0;
  int nseg = 1;
  while (nseg < 16 && (size_t)(N_/nseg)*J_*B_ > avail) nseg <<= 1;
  const int SL = N_/nseg;

  detect_zero<<<64, 256, 0, stream>>>((const u16*)X, (const u16*)Wm, flags, s_acc);
  transpose_x<<<512, 256, 0, stream>>>(X, flags, X_t);

  // routing iter 0: c uniform
  accum_kernel<0><<<dim3(N_/64, J_), 256, 0, stream>>>(X_t, Wm, flags, nullptr, s_acc, 0);
  squash_kernel<0><<<8, 256, 0, stream>>>(s_acc, o_t, flags, nullptr);

  // routing iters 1,2: logits(o_t accumulated) -> softmax c -> accumulate
  for (int r=1; r<=2; ++r){
    for (int sgi=0; sgi<nseg; ++sgi){
      const int n0 = sgi*SL;
      logits_kernel<<<SL/4, 256, 0, stream>>>(X_t, Wm, flags, o_t, c_buf, n0);
      accum_kernel<1><<<dim3(SL/64, J_), 256, 0, stream>>>(X_t, Wm, flags, c_buf, s_acc, n0);
    }
    if (r==1) squash_kernel<1><<<8, 256, 0, stream>>>(s_acc, o_t, flags, nullptr);
    else      squash_kernel<2><<<8, 256, 0, stream>>>(s_acc, o_t, flags, d_out);
  }
}

// Round 5
// 1495.548 us; speedup vs baseline: 2.5666x; 1.2086x over previous
//
#include <hip/hip_runtime.h>
#include <hip/hip_bf16.h>

typedef unsigned int  u32;
typedef unsigned short u16;
typedef __attribute__((ext_vector_type(8)))  short short8;
typedef __attribute__((ext_vector_type(16))) float f32x16;

#define B_ 64
#define N_ 2048
#define I_ 16
#define J_ 32
#define K_ 32
#define BJK 65536
#define LSTR 36        // LDS row stride (floats) for logits transpose; 16B-aligned rows

__device__ __forceinline__ float bf2f(u16 u){ return __uint_as_float(((u32)u)<<16); }
__device__ __forceinline__ short f2bf(float f){
  __hip_bfloat16 h = __float2bfloat16(f);
  short s; __builtin_memcpy(&s, &h, 2); return s;
}

// ---- dtype sniffer + zero s_acc (proven rounds 2-4) ---------------------
__global__ __launch_bounds__(256) void detect_zero(const u16* __restrict__ X,
                                                   const u16* __restrict__ W,
                                                   int* __restrict__ flags,
                                                   float* __restrict__ s_acc)
{
  float4* z = (float4*)s_acc;
  z[blockIdx.x*256 + threadIdx.x] = make_float4(0.f,0.f,0.f,0.f);
  if (blockIdx.x == 0) {
    __shared__ int sx, sw;
    if (threadIdx.x == 0){ sx = 0; sw = 0; }
    __syncthreads();
    int bx = 0, bw = 0;
    for (int i = threadIdx.x; i < 8192; i += 256){
      int ex = (X[2*i] >> 7) & 0xFF;
      int ew = (W[2*i] >> 7) & 0xFF;
      if (ex >= 0x90) bx = 1;
      if (ew >= 0x90) bw = 1;
    }
    if (bx) atomicOr(&sx, 1);
    if (bw) atomicOr(&sw, 1);
    __syncthreads();
    if (threadIdx.x == 0){ flags[0] = sx; flags[1] = sw; }
  }
}

// ---- pack X into A-fragment order (bf16) --------------------------------
// X_p[n][lane][t*8+q] = bf16( x[b = t*32+(lane&31)][n][i = (lane>>5)*8+q] )
// so a wave's dwordx4 load at (n, lane) yields the exact mfma_32x32x16 A frag.
__global__ __launch_bounds__(256) void pack_x(const void* __restrict__ Xv,
                                              const int* __restrict__ flags,
                                              u16* __restrict__ X_p)
{
  const int l = threadIdx.x & 63, w = threadIdx.x >> 6;
  const int n = blockIdx.x*4 + w;
  const bool xf32 = flags[0] != 0;
  const int ih = (l>>5)*8;
  u16 out[16];
  #pragma unroll
  for (int t=0;t<2;++t){
    const int b = t*32 + (l&31);
    if (xf32){
      const float4* xp = (const float4*)((const float*)Xv + ((size_t)b*N_ + n)*I_ + ih);
      float4 v0 = xp[0], v1 = xp[1];
      out[t*8+0]=(u16)f2bf(v0.x); out[t*8+1]=(u16)f2bf(v0.y);
      out[t*8+2]=(u16)f2bf(v0.z); out[t*8+3]=(u16)f2bf(v0.w);
      out[t*8+4]=(u16)f2bf(v1.x); out[t*8+5]=(u16)f2bf(v1.y);
      out[t*8+6]=(u16)f2bf(v1.z); out[t*8+7]=(u16)f2bf(v1.w);
    } else {
      const u16* xp = (const u16*)Xv + ((size_t)b*N_ + n)*I_ + ih;
      #pragma unroll
      for (int q=0;q<8;++q) out[t*8+q] = xp[q];
    }
  }
  u16* dst = X_p + (size_t)n*1024 + l*16;
  short8 s0, s1;
  #pragma unroll
  for (int q=0;q<8;++q){ s0[q]=(short)out[q]; s1[q]=(short)out[8+q]; }
  *(short8*)dst = s0;
  *(short8*)(dst+8) = s1;
}

// ---- W B-fragment load: B[k=i][col=k_caps] = W[j][n][k_caps][i] ---------
__device__ __forceinline__ short8 wfrag_f32(const float* wp){
  float4 w0 = *(const float4*)wp;
  float4 w1 = *(const float4*)(wp+4);
  short8 r;
  r[0]=f2bf(w0.x); r[1]=f2bf(w0.y); r[2]=f2bf(w0.z); r[3]=f2bf(w0.w);
  r[4]=f2bf(w1.x); r[5]=f2bf(w1.y); r[6]=f2bf(w1.z); r[7]=f2bf(w1.w);
  return r;
}

// ---- accum: s[b,j,k] += sum_n c * u_hat via MFMA ------------------------
// grid (64, J): block = 64-chunk/2... blockIdx.x covers 32 n, wave covers 8.
// R==0: c uniform (applied later in squash<0> as 1/32).
template<int R, bool WF32>
__device__ __forceinline__ void accum_body(
    const u16* __restrict__ X_p, const void* __restrict__ Wv,
    const float* __restrict__ c_buf, float* __restrict__ s_acc)
{
  const int l  = threadIdx.x & 63;
  const int w  = threadIdx.x >> 6;
  const int j  = blockIdx.y;
  const int n0 = blockIdx.x*32 + w*8;
  const int kc = l & 31;            // A-row b%32 AND C-col k (both = lane&31)
  const int ih = (l >> 5) * 8;

  f32x16 C0, C1;
  #pragma unroll
  for (int r=0;r<16;++r){ C0[r]=0.f; C1[r]=0.f; }

  #pragma unroll 2
  for (int t=0;t<8;++t){
    const int n = n0 + t;
    const u16* xp = X_p + (size_t)n*1024 + l*16;
    short8 xa0 = *(const short8*)xp;
    short8 xa1 = *(const short8*)(xp+8);
    short8 a0, a1;
    if constexpr (R==0){ a0 = xa0; a1 = xa1; }
    else {
      const float c0 = c_buf[((size_t)n*J_ + j)*64 + kc];
      const float c1 = c_buf[((size_t)n*J_ + j)*64 + 32 + kc];
      #pragma unroll
      for (int q=0;q<8;++q){
        a0[q] = f2bf(c0 * bf2f((u16)xa0[q]));
        a1[q] = f2bf(c1 * bf2f((u16)xa1[q]));
      }
    }
    short8 bfr;
    if constexpr (WF32)
      bfr = wfrag_f32((const float*)Wv + ((size_t)j*N_ + n)*512 + kc*16 + ih);
    else
      bfr = *(const short8*)((const u16*)Wv + ((size_t)j*N_ + n)*512 + kc*16 + ih);
    C0 = __builtin_amdgcn_mfma_f32_32x32x16_bf16(a0, bfr, C0, 0,0,0);
    C1 = __builtin_amdgcn_mfma_f32_32x32x16_bf16(a1, bfr, C1, 0,0,0);
  }

  const int h = l >> 5;
  #pragma unroll
  for (int r=0;r<16;++r){
    const int brow = (r&3) + 8*(r>>2) + 4*h;     // C row within 32-tile
    atomicAdd(&s_acc[((size_t)j*K_ + kc)*64 + brow],      C0[r]);
    atomicAdd(&s_acc[((size_t)j*K_ + kc)*64 + 32 + brow], C1[r]);
  }
}

template<int R>
__global__ __launch_bounds__(256) void accum_kernel(
    const u16* __restrict__ X_p, const void* __restrict__ Wv,
    const int* __restrict__ flags, const float* __restrict__ c_buf,
    float* __restrict__ s_acc)
{
  if (flags[1]) accum_body<R,true >(X_p, Wv, c_buf, s_acc);
  else          accum_body<R,false>(X_p, Wv, c_buf, s_acc);
}

// ---- logits: c_buf[n][j][b] = sum_k o[b,j,k]*u_hat[b,j,n,k] -------------
// u_hat tiles via MFMA; LDS transpose to rows; in-lane o-dot; coalesced store.
template<bool WF32>
__device__ __forceinline__ void logits_body(
    const u16* __restrict__ X_p, const void* __restrict__ Wv,
    const float* __restrict__ o_t, float* __restrict__ c_buf)
{
  __shared__ float tr[4][64*LSTR];
  const int l  = threadIdx.x & 63;
  const int w  = threadIdx.x >> 6;
  const int j  = blockIdx.y;
  const int n0 = blockIdx.x*32 + w*8;
  const int kc = l & 31;
  const int h  = l >> 5;
  const int ih = h*8;

  float o2[32];                       // o for my output row b=l
  #pragma unroll
  for (int k=0;k<32;++k) o2[k] = o_t[((size_t)j*K_ + k)*64 + l];

  float* myrow = &tr[w][l*LSTR];

  #pragma unroll 1
  for (int t=0;t<8;++t){
    const int n = n0 + t;
    const u16* xp = X_p + (size_t)n*1024 + l*16;
    short8 xa0 = *(const short8*)xp;
    short8 xa1 = *(const short8*)(xp+8);
    short8 bfr;
    if constexpr (WF32)
      bfr = wfrag_f32((const float*)Wv + ((size_t)j*N_ + n)*512 + kc*16 + ih);
    else
      bfr = *(const short8*)((const u16*)Wv + ((size_t)j*N_ + n)*512 + kc*16 + ih);
    f32x16 C0, C1;
    #pragma unroll
    for (int r=0;r<16;++r){ C0[r]=0.f; C1[r]=0.f; }
    C0 = __builtin_amdgcn_mfma_f32_32x32x16_bf16(xa0, bfr, C0, 0,0,0);
    C1 = __builtin_amdgcn_mfma_f32_32x32x16_bf16(xa1, bfr, C1, 0,0,0);
    // transpose C-layout -> rows: tr[b][k] = u_hat[b,k]
    #pragma unroll
    for (int r=0;r<16;++r){
      const int brow = (r&3) + 8*(r>>2) + 4*h;
      tr[w][brow*LSTR + kc]      = C0[r];
      tr[w][(32+brow)*LSTR + kc] = C1[r];
    }
    __asm__ volatile("s_waitcnt lgkmcnt(0)" ::: "memory");
    float d = 0.f;
    #pragma unroll
    for (int q=0;q<8;++q){
      float4 uq = *(const float4*)(myrow + 4*q);
      d += uq.x*o2[4*q] + uq.y*o2[4*q+1] + uq.z*o2[4*q+2] + uq.w*o2[4*q+3];
    }
    c_buf[((size_t)n*J_ + j)*64 + l] = d;
  }
}

__global__ __launch_bounds__(256) void logits_kernel(
    const u16* __restrict__ X_p, const void* __restrict__ Wv,
    const int* __restrict__ flags, const float* __restrict__ o_t,
    float* __restrict__ c_buf)
{
  if (flags[1]) logits_body<true >(X_p, Wv, o_t, c_buf);
  else          logits_body<false>(X_p, Wv, o_t, c_buf);
}

// ---- softmax over j, in-lane (lane=b), per n ----------------------------
__global__ __launch_bounds__(256) void softmax_kernel(float* __restrict__ c_buf)
{
  const int l = threadIdx.x & 63, w = threadIdx.x >> 6;
  const int n = blockIdx.x*4 + w;
  float* p = c_buf + (size_t)n*J_*64 + l;
  float e[32]; float m = -1e30f;
  #pragma unroll
  for (int jj=0;jj<32;++jj){ e[jj] = p[jj*64]; m = fmaxf(m, e[jj]); }
  float s = 0.f;
  #pragma unroll
  for (int jj=0;jj<32;++jj){ e[jj] = __expf(e[jj]-m); s += e[jj]; }
  const float inv = 1.f/s;
  #pragma unroll
  for (int jj=0;jj<32;++jj) p[jj*64] = e[jj]*inv;
}

// ---- squash + o_t maintenance + s_acc re-zero ---------------------------
// R==0: o_t = squash(s/32). R==1: o_t += squash(s). R==2: write d_out.
template<int R>
__global__ __launch_bounds__(256) void squash_kernel(
    float* __restrict__ s_acc, float* __restrict__ o_t,
    const int* __restrict__ flags, void* __restrict__ d_out)
{
  const int l = threadIdx.x & 63, w = threadIdx.x >> 6;
  const int j = blockIdx.x*4 + w;
  float v[K_]; float sq = 0.f;
  #pragma unroll
  for (int k=0;k<K_;++k){
    float t = s_acc[((size_t)j*K_ + k)*64 + l];
    if constexpr (R==0) t *= (1.0f/32.0f);
    v[k] = t; sq += t*t;
    s_acc[((size_t)j*K_ + k)*64 + l] = 0.f;
  }
  const float scale = sq/(1.f+sq)/sqrtf(sq+1e-7f);
  if constexpr (R==0){
    #pragma unroll
    for (int k=0;k<K_;++k) o_t[((size_t)j*K_ + k)*64 + l] = scale*v[k];
  } else if constexpr (R==1){
    #pragma unroll
    for (int k=0;k<K_;++k) o_t[((size_t)j*K_ + k)*64 + l] += scale*v[k];
  } else {
    const bool f32o = (flags[0]!=0) && (flags[1]!=0);
    if (f32o){
      float* po = (float*)d_out;
      #pragma unroll
      for (int k=0;k<K_;++k) po[(size_t)l*(J_*K_) + j*K_ + k] = scale*v[k];
    } else {
      __hip_bfloat16* po = (__hip_bfloat16*)d_out;
      #pragma unroll
      for (int k=0;k<K_;++k) po[(size_t)l*(J_*K_) + j*K_ + k] = __float2bfloat16(scale*v[k]);
    }
  }
}

extern "C" void kernel_launch(void* const* d_in, const int* in_sizes, int n_in,
                              void* d_out, int out_size, void* d_ws, size_t ws_size,
                              hipStream_t stream)
{
  const void* X  = d_in[0];   // [B][N][I]     (dtype sniffed)
  const void* Wm = d_in[1];   // [J][N][K][I]  (dtype sniffed)

  float* s_acc = (float*)d_ws;                       // 65536 f32
  float* o_t   = s_acc + BJK;                        // 65536 f32, layout [j][k][b]
  int*   flags = (int*)(o_t + BJK);                  // 64-f32 pad
  u16*   X_p   = (u16*)((float*)d_ws + 2*BJK + 64);  // 2048*1024 u16 (4 MB)
  float* c_buf = (float*)(X_p + (size_t)N_*1024);    // 2048*32*64 f32 (16.7 MB)
  // total ~21.5 MB (< 34 MB proven available)

  const dim3 blk(256);
  const dim3 g_mf(64, J_);    // 64 n-chunks x 32 j
  detect_zero<<<64, blk, 0, stream>>>((const u16*)X, (const u16*)Wm, flags, s_acc);
  pack_x<<<N_/4, blk, 0, stream>>>(X, flags, X_p);

  // iter 0: uniform c
  accum_kernel<0><<<g_mf, blk, 0, stream>>>(X_p, Wm, flags, nullptr, s_acc);
  squash_kernel<0><<<8, blk, 0, stream>>>(s_acc, o_t, flags, nullptr);

  // iters 1,2
  logits_kernel<<<g_mf, blk, 0, stream>>>(X_p, Wm, flags, o_t, c_buf);
  softmax_kernel<<<N_/4, blk, 0, stream>>>(c_buf);
  accum_kernel<1><<<g_mf, blk, 0, stream>>>(X_p, Wm, flags, c_buf, s_acc);
  squash_kernel<1><<<8, blk, 0, stream>>>(s_acc, o_t, flags, nullptr);

  logits_kernel<<<g_mf, blk, 0, stream>>>(X_p, Wm, flags, o_t, c_buf);
  softmax_kernel<<<N_/4, blk, 0, stream>>>(c_buf);
  accum_kernel<1><<<g_mf, blk, 0, stream>>>(X_p, Wm, flags, c_buf, s_acc);
  squash_kernel<2><<<8, blk, 0, stream>>>(s_acc, o_t, flags, d_out);
}

// Round 6
// 409.630 us; speedup vs baseline: 9.3707x; 3.6510x over previous
//
#include <hip/hip_runtime.h>
#include <hip/hip_bf16.h>

typedef unsigned int  u32;
typedef unsigned short u16;
typedef __attribute__((ext_vector_type(8)))  short short8;
typedef __attribute__((ext_vector_type(16))) float f32x16;

#define B_ 64
#define N_ 2048
#define I_ 16
#define J_ 32
#define K_ 32
#define BJK 65536
#define LSTR 36        // LDS row stride (floats) for logits transpose
#define CH_  32        // n-chunks for accum (block covers 64 n, wave 16)

__device__ __forceinline__ float bf2f(u16 u){ return __uint_as_float(((u32)u)<<16); }
__device__ __forceinline__ short f2bf(float f){
  __hip_bfloat16 h = __float2bfloat16(f);
  short s; __builtin_memcpy(&s, &h, 2); return s;
}

// ---- dtype sniffer + zero s_acc (proven rounds 2-5) ---------------------
__global__ __launch_bounds__(256) void detect_zero(const u16* __restrict__ X,
                                                   const u16* __restrict__ W,
                                                   int* __restrict__ flags,
                                                   float* __restrict__ s_acc)
{
  float4* z = (float4*)s_acc;
  z[blockIdx.x*256 + threadIdx.x] = make_float4(0.f,0.f,0.f,0.f);
  if (blockIdx.x == 0) {
    __shared__ int sx, sw;
    if (threadIdx.x == 0){ sx = 0; sw = 0; }
    __syncthreads();
    int bx = 0, bw = 0;
    for (int i = threadIdx.x; i < 8192; i += 256){
      int ex = (X[2*i] >> 7) & 0xFF;
      int ew = (W[2*i] >> 7) & 0xFF;
      if (ex >= 0x90) bx = 1;
      if (ew >= 0x90) bw = 1;
    }
    if (bx) atomicOr(&sx, 1);
    if (bw) atomicOr(&sw, 1);
    __syncthreads();
    if (threadIdx.x == 0){ flags[0] = sx; flags[1] = sw; }
  }
}

// ---- pack X into A-fragment order (bf16) --------------------------------
// X_p[n][lane][t*8+q] = bf16( x[b = t*32+(lane&31)][n][i = (lane>>5)*8+q] )
__global__ __launch_bounds__(256) void pack_x(const void* __restrict__ Xv,
                                              const int* __restrict__ flags,
                                              u16* __restrict__ X_p)
{
  const int l = threadIdx.x & 63, w = threadIdx.x >> 6;
  const int n = blockIdx.x*4 + w;
  const bool xf32 = flags[0] != 0;
  const int ih = (l>>5)*8;
  u16 out[16];
  #pragma unroll
  for (int t=0;t<2;++t){
    const int b = t*32 + (l&31);
    if (xf32){
      const float4* xp = (const float4*)((const float*)Xv + ((size_t)b*N_ + n)*I_ + ih);
      float4 v0 = xp[0], v1 = xp[1];
      out[t*8+0]=(u16)f2bf(v0.x); out[t*8+1]=(u16)f2bf(v0.y);
      out[t*8+2]=(u16)f2bf(v0.z); out[t*8+3]=(u16)f2bf(v0.w);
      out[t*8+4]=(u16)f2bf(v1.x); out[t*8+5]=(u16)f2bf(v1.y);
      out[t*8+6]=(u16)f2bf(v1.z); out[t*8+7]=(u16)f2bf(v1.w);
    } else {
      const u16* xp = (const u16*)Xv + ((size_t)b*N_ + n)*I_ + ih;
      #pragma unroll
      for (int q=0;q<8;++q) out[t*8+q] = xp[q];
    }
  }
  u16* dst = X_p + (size_t)n*1024 + l*16;
  short8 s0, s1;
  #pragma unroll
  for (int q=0;q<8;++q){ s0[q]=(short)out[q]; s1[q]=(short)out[8+q]; }
  *(short8*)dst = s0;
  *(short8*)(dst+8) = s1;
}

// ---- W B-fragment load (fp32 path) --------------------------------------
__device__ __forceinline__ short8 wfrag_f32(const float* wp){
  float4 w0 = *(const float4*)wp;
  float4 w1 = *(const float4*)(wp+4);
  short8 r;
  r[0]=f2bf(w0.x); r[1]=f2bf(w0.y); r[2]=f2bf(w0.z); r[3]=f2bf(w0.w);
  r[4]=f2bf(w1.x); r[5]=f2bf(w1.y); r[6]=f2bf(w1.z); r[7]=f2bf(w1.w);
  return r;
}

// ---- accum: per-(chunk,j) partial of s[b,j,k] via MFMA, NO atomics ------
// grid (CH_, J). Block covers 64 n; wave w covers 16. LDS-reduce 4 waves,
// write one 8KB partial part[ch][j][r(32)][l(64)], coalesced.
template<int R, bool WF32>
__device__ __forceinline__ void accum_body(
    const u16* __restrict__ X_p, const void* __restrict__ Wv,
    const float* __restrict__ c_buf, float* __restrict__ part)
{
  __shared__ float red[4][2048];
  const int l  = threadIdx.x & 63;
  const int w  = threadIdx.x >> 6;
  const int j  = blockIdx.y;
  const int ch = blockIdx.x;
  const int n0 = ch*64 + w*16;
  const int kc = l & 31;
  const int ih = (l >> 5) * 8;

  f32x16 C0, C1;
  #pragma unroll
  for (int r=0;r<16;++r){ C0[r]=0.f; C1[r]=0.f; }

  #pragma unroll 4
  for (int t=0;t<16;++t){
    const int n = n0 + t;
    const u16* xp = X_p + (size_t)n*1024 + l*16;
    short8 xa0 = *(const short8*)xp;
    short8 xa1 = *(const short8*)(xp+8);
    short8 a0, a1;
    if constexpr (R==0){ a0 = xa0; a1 = xa1; }
    else {
      const float c0 = c_buf[((size_t)n*J_ + j)*64 + kc];
      const float c1 = c_buf[((size_t)n*J_ + j)*64 + 32 + kc];
      #pragma unroll
      for (int q=0;q<8;++q){
        a0[q] = f2bf(c0 * bf2f((u16)xa0[q]));
        a1[q] = f2bf(c1 * bf2f((u16)xa1[q]));
      }
    }
    short8 bfr;
    if constexpr (WF32)
      bfr = wfrag_f32((const float*)Wv + ((size_t)j*N_ + n)*512 + kc*16 + ih);
    else
      bfr = *(const short8*)((const u16*)Wv + ((size_t)j*N_ + n)*512 + kc*16 + ih);
    C0 = __builtin_amdgcn_mfma_f32_32x32x16_bf16(a0, bfr, C0, 0,0,0);
    C1 = __builtin_amdgcn_mfma_f32_32x32x16_bf16(a1, bfr, C1, 0,0,0);
  }

  // raw C-layout into LDS: red[w][r*64+l] (r<16: C0, r>=16: C1)
  #pragma unroll
  for (int r=0;r<16;++r){
    red[w][r*64 + l]      = C0[r];
    red[w][(16+r)*64 + l] = C1[r];
  }
  __syncthreads();

  // cross-wave sum -> one partial per block, coalesced store
  float* dst = part + ((size_t)ch*J_ + j)*2048;
  #pragma unroll
  for (int p = threadIdx.x; p < 2048; p += 256)
    dst[p] = red[0][p] + red[1][p] + red[2][p] + red[3][p];
}

template<int R>
__global__ __launch_bounds__(256) void accum_kernel(
    const u16* __restrict__ X_p, const void* __restrict__ Wv,
    const int* __restrict__ flags, const float* __restrict__ c_buf,
    float* __restrict__ part)
{
  if (flags[1]) accum_body<R,true >(X_p, Wv, c_buf, part);
  else          accum_body<R,false>(X_p, Wv, c_buf, part);
}

// ---- reduce partials over chunks -> s_acc[j][k][b] ----------------------
// grid (J); thread sums 8 p's over CH_ chunks (coalesced in p).
__global__ __launch_bounds__(256) void reduce_kernel(
    const float* __restrict__ part, float* __restrict__ s_acc)
{
  const int j = blockIdx.x;
  #pragma unroll
  for (int p = threadIdx.x; p < 2048; p += 256){
    float sum = 0.f;
    #pragma unroll 4
    for (int ch=0; ch<CH_; ++ch)
      sum += part[((size_t)ch*J_ + j)*2048 + p];
    const int r  = p >> 6, l = p & 63;
    const int kc = l & 31, h = l >> 5;
    const int rr = r & 15, tile = r >> 4;
    const int b  = tile*32 + (rr&3) + 8*(rr>>2) + 4*h;
    s_acc[((size_t)j*K_ + kc)*64 + b] = sum;
  }
}

// ---- logits: c_buf[n][j][b] = sum_k o[b,j,k]*u_hat[b,j,n,k] -------------
template<bool WF32>
__device__ __forceinline__ void logits_body(
    const u16* __restrict__ X_p, const void* __restrict__ Wv,
    const float* __restrict__ o_t, float* __restrict__ c_buf)
{
  __shared__ float tr[4][64*LSTR];
  const int l  = threadIdx.x & 63;
  const int w  = threadIdx.x >> 6;
  const int j  = blockIdx.y;
  const int n0 = blockIdx.x*32 + w*8;
  const int kc = l & 31;
  const int h  = l >> 5;
  const int ih = h*8;

  float o2[32];
  #pragma unroll
  for (int k=0;k<32;++k) o2[k] = o_t[((size_t)j*K_ + k)*64 + l];

  float* myrow = &tr[w][l*LSTR];

  #pragma unroll 1
  for (int t=0;t<8;++t){
    const int n = n0 + t;
    const u16* xp = X_p + (size_t)n*1024 + l*16;
    short8 xa0 = *(const short8*)xp;
    short8 xa1 = *(const short8*)(xp+8);
    short8 bfr;
    if constexpr (WF32)
      bfr = wfrag_f32((const float*)Wv + ((size_t)j*N_ + n)*512 + kc*16 + ih);
    else
      bfr = *(const short8*)((const u16*)Wv + ((size_t)j*N_ + n)*512 + kc*16 + ih);
    f32x16 C0, C1;
    #pragma unroll
    for (int r=0;r<16;++r){ C0[r]=0.f; C1[r]=0.f; }
    C0 = __builtin_amdgcn_mfma_f32_32x32x16_bf16(xa0, bfr, C0, 0,0,0);
    C1 = __builtin_amdgcn_mfma_f32_32x32x16_bf16(xa1, bfr, C1, 0,0,0);
    #pragma unroll
    for (int r=0;r<16;++r){
      const int brow = (r&3) + 8*(r>>2) + 4*h;
      tr[w][brow*LSTR + kc]      = C0[r];
      tr[w][(32+brow)*LSTR + kc] = C1[r];
    }
    __asm__ volatile("s_waitcnt lgkmcnt(0)" ::: "memory");
    float d = 0.f;
    #pragma unroll
    for (int q=0;q<8;++q){
      float4 uq = *(const float4*)(myrow + 4*q);
      d += uq.x*o2[4*q] + uq.y*o2[4*q+1] + uq.z*o2[4*q+2] + uq.w*o2[4*q+3];
    }
    c_buf[((size_t)n*J_ + j)*64 + l] = d;
  }
}

__global__ __launch_bounds__(256) void logits_kernel(
    const u16* __restrict__ X_p, const void* __restrict__ Wv,
    const int* __restrict__ flags, const float* __restrict__ o_t,
    float* __restrict__ c_buf)
{
  if (flags[1]) logits_body<true >(X_p, Wv, o_t, c_buf);
  else          logits_body<false>(X_p, Wv, o_t, c_buf);
}

// ---- softmax over j, in-lane (lane=b), per n ----------------------------
__global__ __launch_bounds__(256) void softmax_kernel(float* __restrict__ c_buf)
{
  const int l = threadIdx.x & 63, w = threadIdx.x >> 6;
  const int n = blockIdx.x*4 + w;
  float* p = c_buf + (size_t)n*J_*64 + l;
  float e[32]; float m = -1e30f;
  #pragma unroll
  for (int jj=0;jj<32;++jj){ e[jj] = p[jj*64]; m = fmaxf(m, e[jj]); }
  float s = 0.f;
  #pragma unroll
  for (int jj=0;jj<32;++jj){ e[jj] = __expf(e[jj]-m); s += e[jj]; }
  const float inv = 1.f/s;
  #pragma unroll
  for (int jj=0;jj<32;++jj) p[jj*64] = e[jj]*inv;
}

// ---- squash + o_t maintenance -------------------------------------------
// R==0: o_t = squash(s/32). R==1: o_t += squash(s). R==2: write d_out.
template<int R>
__global__ __launch_bounds__(256) void squash_kernel(
    float* __restrict__ s_acc, float* __restrict__ o_t,
    const int* __restrict__ flags, void* __restrict__ d_out)
{
  const int l = threadIdx.x & 63, w = threadIdx.x >> 6;
  const int j = blockIdx.x*4 + w;
  float v[K_]; float sq = 0.f;
  #pragma unroll
  for (int k=0;k<K_;++k){
    float t = s_acc[((size_t)j*K_ + k)*64 + l];
    if constexpr (R==0) t *= (1.0f/32.0f);
    v[k] = t; sq += t*t;
  }
  const float scale = sq/(1.f+sq)/sqrtf(sq+1e-7f);
  if constexpr (R==0){
    #pragma unroll
    for (int k=0;k<K_;++k) o_t[((size_t)j*K_ + k)*64 + l] = scale*v[k];
  } else if constexpr (R==1){
    #pragma unroll
    for (int k=0;k<K_;++k) o_t[((size_t)j*K_ + k)*64 + l] += scale*v[k];
  } else {
    const bool f32o = (flags[0]!=0) && (flags[1]!=0);
    if (f32o){
      float* po = (float*)d_out;
      #pragma unroll
      for (int k=0;k<K_;++k) po[(size_t)l*(J_*K_) + j*K_ + k] = scale*v[k];
    } else {
      __hip_bfloat16* po = (__hip_bfloat16*)d_out;
      #pragma unroll
      for (int k=0;k<K_;++k) po[(size_t)l*(J_*K_) + j*K_ + k] = __float2bfloat16(scale*v[k]);
    }
  }
}

extern "C" void kernel_launch(void* const* d_in, const int* in_sizes, int n_in,
                              void* d_out, int out_size, void* d_ws, size_t ws_size,
                              hipStream_t stream)
{
  const void* X  = d_in[0];   // [B][N][I]     (dtype sniffed)
  const void* Wm = d_in[1];   // [J][N][K][I]  (dtype sniffed)

  float* s_acc = (float*)d_ws;                       // 65536 f32
  float* o_t   = s_acc + BJK;                        // 65536 f32, [j][k][b]
  int*   flags = (int*)(o_t + BJK);                  // 64-f32 pad
  u16*   X_p   = (u16*)((float*)d_ws + 2*BJK + 64);  // 2048*1024 u16 (4 MB)
  float* c_buf = (float*)(X_p + (size_t)N_*1024);    // 2048*32*64 f32 (16.8 MB)
  float* part  = c_buf + (size_t)N_*J_*64;           // CH_*32*2048 f32 (8.4 MB)
  // total ~29.7 MB (< 33.5 MB proven available)

  const dim3 blk(256);
  const dim3 g_ac(CH_, J_);    // accum: 1024 blocks
  const dim3 g_lg(64,  J_);    // logits: 2048 blocks

  detect_zero<<<64, blk, 0, stream>>>((const u16*)X, (const u16*)Wm, flags, s_acc);
  pack_x<<<N_/4, blk, 0, stream>>>(X, flags, X_p);

  // iter 0: uniform c (1/32 folded into squash<0>)
  accum_kernel<0><<<g_ac, blk, 0, stream>>>(X_p, Wm, flags, nullptr, part);
  reduce_kernel<<<J_, blk, 0, stream>>>(part, s_acc);
  squash_kernel<0><<<8, blk, 0, stream>>>(s_acc, o_t, flags, nullptr);

  // iters 1,2
  logits_kernel<<<g_lg, blk, 0, stream>>>(X_p, Wm, flags, o_t, c_buf);
  softmax_kernel<<<N_/4, blk, 0, stream>>>(c_buf);
  accum_kernel<1><<<g_ac, blk, 0, stream>>>(X_p, Wm, flags, c_buf, part);
  reduce_kernel<<<J_, blk, 0, stream>>>(part, s_acc);
  squash_kernel<1><<<8, blk, 0, stream>>>(s_acc, o_t, flags, nullptr);

  logits_kernel<<<g_lg, blk, 0, stream>>>(X_p, Wm, flags, o_t, c_buf);
  softmax_kernel<<<N_/4, blk, 0, stream>>>(c_buf);
  accum_kernel<1><<<g_ac, blk, 0, stream>>>(X_p, Wm, flags, c_buf, part);
  reduce_kernel<<<J_, blk, 0, stream>>>(part, s_acc);
  squash_kernel<2><<<8, blk, 0, stream>>>(s_acc, o_t, flags, d_out);
}

// Round 7
// 389.489 us; speedup vs baseline: 9.8553x; 1.0517x over previous
//
#include <hip/hip_runtime.h>
#include <hip/hip_bf16.h>

typedef unsigned int  u32;
typedef unsigned short u16;
typedef __attribute__((ext_vector_type(8)))  short short8;
typedef __attribute__((ext_vector_type(16))) float f32x16;

#define B_ 64
#define N_ 2048
#define I_ 16
#define J_ 32
#define K_ 32
#define BJK 65536
#define CH_  32        // n-chunks for accum (block covers 64 n, wave 16)
#define WTOT ((size_t)J_*N_*K_*I_)   // 33,554,432 W elements

__device__ __forceinline__ float bf2f(u16 u){ return __uint_as_float(((u32)u)<<16); }
__device__ __forceinline__ short f2bf(float f){
  __hip_bfloat16 h = __float2bfloat16(f);
  short s; __builtin_memcpy(&s, &h, 2); return s;
}

// ---- dtype sniffer + zero s_acc (proven rounds 2-6) ---------------------
__global__ __launch_bounds__(256) void detect_zero(const u16* __restrict__ X,
                                                   const u16* __restrict__ W,
                                                   int* __restrict__ flags,
                                                   float* __restrict__ s_acc)
{
  float4* z = (float4*)s_acc;
  z[blockIdx.x*256 + threadIdx.x] = make_float4(0.f,0.f,0.f,0.f);
  if (blockIdx.x == 0) {
    __shared__ int sx, sw;
    if (threadIdx.x == 0){ sx = 0; sw = 0; }
    __syncthreads();
    int bx = 0, bw = 0;
    for (int i = threadIdx.x; i < 8192; i += 256){
      int ex = (X[2*i] >> 7) & 0xFF;
      int ew = (W[2*i] >> 7) & 0xFF;
      if (ex >= 0x90) bx = 1;
      if (ew >= 0x90) bw = 1;
    }
    if (bx) atomicOr(&sx, 1);
    if (bw) atomicOr(&sw, 1);
    __syncthreads();
    if (threadIdx.x == 0){ flags[0] = sx; flags[1] = sw; }
  }
}

// ---- pack X into A/B-fragment order (bf16) ------------------------------
// X_p[n][lane][t*8+q] = bf16( x[b = t*32+(lane&31)][n][i = (lane>>5)*8+q] )
__global__ __launch_bounds__(256) void pack_x(const void* __restrict__ Xv,
                                              const int* __restrict__ flags,
                                              u16* __restrict__ X_p)
{
  const int l = threadIdx.x & 63, w = threadIdx.x >> 6;
  const int n = blockIdx.x*4 + w;
  const bool xf32 = flags[0] != 0;
  const int ih = (l>>5)*8;
  u16 out[16];
  #pragma unroll
  for (int t=0;t<2;++t){
    const int b = t*32 + (l&31);
    if (xf32){
      const float4* xp = (const float4*)((const float*)Xv + ((size_t)b*N_ + n)*I_ + ih);
      float4 v0 = xp[0], v1 = xp[1];
      out[t*8+0]=(u16)f2bf(v0.x); out[t*8+1]=(u16)f2bf(v0.y);
      out[t*8+2]=(u16)f2bf(v0.z); out[t*8+3]=(u16)f2bf(v0.w);
      out[t*8+4]=(u16)f2bf(v1.x); out[t*8+5]=(u16)f2bf(v1.y);
      out[t*8+6]=(u16)f2bf(v1.z); out[t*8+7]=(u16)f2bf(v1.w);
    } else {
      const u16* xp = (const u16*)Xv + ((size_t)b*N_ + n)*I_ + ih;
      #pragma unroll
      for (int q=0;q<8;++q) out[t*8+q] = xp[q];
    }
  }
  u16* dst = X_p + (size_t)n*1024 + l*16;
  short8 s0, s1;
  #pragma unroll
  for (int q=0;q<8;++q){ s0[q]=(short)out[q]; s1[q]=(short)out[8+q]; }
  *(short8*)dst = s0;
  *(short8*)(dst+8) = s1;
}

// ---- pack W -> bf16 (same [j][n][k][i] order), streaming cvt/copy -------
__global__ __launch_bounds__(256) void pack_w(const void* __restrict__ Wv,
                                              const int* __restrict__ flags,
                                              u16* __restrict__ W_p)
{
  const size_t base = ((size_t)blockIdx.x*256 + threadIdx.x)*16;
  if (flags[1]){
    const float4* src = (const float4*)((const float*)Wv + base);
    float4 v0=src[0], v1=src[1], v2=src[2], v3=src[3];
    short8 a, b;
    a[0]=f2bf(v0.x); a[1]=f2bf(v0.y); a[2]=f2bf(v0.z); a[3]=f2bf(v0.w);
    a[4]=f2bf(v1.x); a[5]=f2bf(v1.y); a[6]=f2bf(v1.z); a[7]=f2bf(v1.w);
    b[0]=f2bf(v2.x); b[1]=f2bf(v2.y); b[2]=f2bf(v2.z); b[3]=f2bf(v2.w);
    b[4]=f2bf(v3.x); b[5]=f2bf(v3.y); b[6]=f2bf(v3.z); b[7]=f2bf(v3.w);
    *(short8*)(W_p + base)     = a;
    *(short8*)(W_p + base + 8) = b;
  } else {
    const short8* src = (const short8*)((const u16*)Wv + base);
    *(short8*)(W_p + base)     = src[0];
    *(short8*)(W_p + base + 8) = src[1];
  }
}

// ---- accum: per-(chunk,j) partial of s via MFMA (A=X, B=W), no atomics --
template<int R>
__global__ __launch_bounds__(256) void accum_kernel(
    const u16* __restrict__ X_p, const u16* __restrict__ W_p,
    const float* __restrict__ c_buf, float* __restrict__ part)
{
  __shared__ float red[4][2048];
  const int l  = threadIdx.x & 63;
  const int w  = threadIdx.x >> 6;
  const int j  = blockIdx.y;
  const int ch = blockIdx.x;
  const int n0 = ch*64 + w*16;
  const int kc = l & 31;
  const int ih = (l >> 5) * 8;

  f32x16 C0, C1;
  #pragma unroll
  for (int r=0;r<16;++r){ C0[r]=0.f; C1[r]=0.f; }

  #pragma unroll 4
  for (int t=0;t<16;++t){
    const int n = n0 + t;
    const u16* xp = X_p + (size_t)n*1024 + l*16;
    short8 xa0 = *(const short8*)xp;
    short8 xa1 = *(const short8*)(xp+8);
    short8 a0, a1;
    if constexpr (R==0){ a0 = xa0; a1 = xa1; }
    else {
      const float c0 = c_buf[((size_t)n*J_ + j)*64 + kc];
      const float c1 = c_buf[((size_t)n*J_ + j)*64 + 32 + kc];
      #pragma unroll
      for (int q=0;q<8;++q){
        a0[q] = f2bf(c0 * bf2f((u16)xa0[q]));
        a1[q] = f2bf(c1 * bf2f((u16)xa1[q]));
      }
    }
    short8 bfr = *(const short8*)(W_p + ((size_t)j*N_ + n)*512 + kc*16 + ih);
    C0 = __builtin_amdgcn_mfma_f32_32x32x16_bf16(a0, bfr, C0, 0,0,0);
    C1 = __builtin_amdgcn_mfma_f32_32x32x16_bf16(a1, bfr, C1, 0,0,0);
  }

  #pragma unroll
  for (int r=0;r<16;++r){
    red[w][r*64 + l]      = C0[r];
    red[w][(16+r)*64 + l] = C1[r];
  }
  __syncthreads();

  float* dst = part + ((size_t)ch*J_ + j)*2048;
  #pragma unroll
  for (int p = threadIdx.x; p < 2048; p += 256)
    dst[p] = red[0][p] + red[1][p] + red[2][p] + red[3][p];
}

// ---- reduce partials over chunks -> s_acc[j][k][b] ----------------------
__global__ __launch_bounds__(256) void reduce_kernel(
    const float* __restrict__ part, float* __restrict__ s_acc)
{
  const int j = blockIdx.x;
  #pragma unroll
  for (int p = threadIdx.x; p < 2048; p += 256){
    float sum = 0.f;
    #pragma unroll 4
    for (int ch=0; ch<CH_; ++ch)
      sum += part[((size_t)ch*J_ + j)*2048 + p];
    const int r  = p >> 6, l = p & 63;
    const int kc = l & 31, h = l >> 5;
    const int rr = r & 15, tile = r >> 4;
    const int b  = tile*32 + (rr&3) + 8*(rr>>2) + 4*h;
    s_acc[((size_t)j*K_ + kc)*64 + b] = sum;
  }
}

// ---- logits: LDS-free via operand swap (A=W, B=X => C cols = b) ---------
// c_buf[n][j][b] = sum_k o[b,j,k]*u_hat[b,j,n,k]
__global__ __launch_bounds__(256) void logits_kernel(
    const u16* __restrict__ X_p, const u16* __restrict__ W_p,
    const float* __restrict__ o_t, float* __restrict__ c_buf)
{
  const int l  = threadIdx.x & 63;
  const int w  = threadIdx.x >> 6;
  const int j  = blockIdx.y;
  const int n0 = blockIdx.x*32 + w*8;
  const int kc = l & 31;          // = column index = b (mod 32)
  const int h  = l >> 5;
  const int ih = h*8;

  // o in C-layout, loaded once per block: o_rT[r] = o_t[j][k(r,h)][b_tile]
  float o_r0[16], o_r1[16];
  #pragma unroll
  for (int r=0;r<16;++r){
    const int k = (r&3) + 8*(r>>2) + 4*h;
    o_r0[r] = o_t[((size_t)j*K_ + k)*64 + kc];
    o_r1[r] = o_t[((size_t)j*K_ + k)*64 + 32 + kc];
  }

  #pragma unroll 2
  for (int t=0;t<8;++t){
    const int n = n0 + t;
    const u16* xp = X_p + (size_t)n*1024 + l*16;
    short8 xa0 = *(const short8*)xp;
    short8 xa1 = *(const short8*)(xp+8);
    short8 wfr = *(const short8*)(W_p + ((size_t)j*N_ + n)*512 + kc*16 + ih);
    f32x16 C0, C1;
    #pragma unroll
    for (int r=0;r<16;++r){ C0[r]=0.f; C1[r]=0.f; }
    C0 = __builtin_amdgcn_mfma_f32_32x32x16_bf16(wfr, xa0, C0, 0,0,0);
    C1 = __builtin_amdgcn_mfma_f32_32x32x16_bf16(wfr, xa1, C1, 0,0,0);
    float d0 = 0.f, d1 = 0.f;
    #pragma unroll
    for (int r=0;r<16;++r){ d0 += C0[r]*o_r0[r]; d1 += C1[r]*o_r1[r]; }
    d0 += __shfl_xor(d0, 32, 64);   // merge the two k-halves (same b)
    d1 += __shfl_xor(d1, 32, 64);
    const float val = (l >= 32) ? d1 : d0;   // lane l owns b=l
    c_buf[((size_t)n*J_ + j)*64 + l] = val;
  }
}

// ---- softmax over j, in-lane (lane=b), per n ----------------------------
__global__ __launch_bounds__(256) void softmax_kernel(float* __restrict__ c_buf)
{
  const int l = threadIdx.x & 63, w = threadIdx.x >> 6;
  const int n = blockIdx.x*4 + w;
  float* p = c_buf + (size_t)n*J_*64 + l;
  float e[32]; float m = -1e30f;
  #pragma unroll
  for (int jj=0;jj<32;++jj){ e[jj] = p[jj*64]; m = fmaxf(m, e[jj]); }
  float s = 0.f;
  #pragma unroll
  for (int jj=0;jj<32;++jj){ e[jj] = __expf(e[jj]-m); s += e[jj]; }
  const float inv = 1.f/s;
  #pragma unroll
  for (int jj=0;jj<32;++jj) p[jj*64] = e[jj]*inv;
}

// ---- squash + o_t maintenance -------------------------------------------
template<int R>
__global__ __launch_bounds__(256) void squash_kernel(
    float* __restrict__ s_acc, float* __restrict__ o_t,
    const int* __restrict__ flags, void* __restrict__ d_out)
{
  const int l = threadIdx.x & 63, w = threadIdx.x >> 6;
  const int j = blockIdx.x*4 + w;
  float v[K_]; float sq = 0.f;
  #pragma unroll
  for (int k=0;k<K_;++k){
    float t = s_acc[((size_t)j*K_ + k)*64 + l];
    if constexpr (R==0) t *= (1.0f/32.0f);
    v[k] = t; sq += t*t;
  }
  const float scale = sq/(1.f+sq)/sqrtf(sq+1e-7f);
  if constexpr (R==0){
    #pragma unroll
    for (int k=0;k<K_;++k) o_t[((size_t)j*K_ + k)*64 + l] = scale*v[k];
  } else if constexpr (R==1){
    #pragma unroll
    for (int k=0;k<K_;++k) o_t[((size_t)j*K_ + k)*64 + l] += scale*v[k];
  } else {
    const bool f32o = (flags[0]!=0) && (flags[1]!=0);
    if (f32o){
      float* po = (float*)d_out;
      #pragma unroll
      for (int k=0;k<K_;++k) po[(size_t)l*(J_*K_) + j*K_ + k] = scale*v[k];
    } else {
      __hip_bfloat16* po = (__hip_bfloat16*)d_out;
      #pragma unroll
      for (int k=0;k<K_;++k) po[(size_t)l*(J_*K_) + j*K_ + k] = __float2bfloat16(scale*v[k]);
    }
  }
}

extern "C" void kernel_launch(void* const* d_in, const int* in_sizes, int n_in,
                              void* d_out, int out_size, void* d_ws, size_t ws_size,
                              hipStream_t stream)
{
  const void* X  = d_in[0];   // [B][N][I]     (dtype sniffed)
  const void* Wm = d_in[1];   // [J][N][K][I]  (dtype sniffed)

  float* s_acc = (float*)d_ws;                       // 65536 f32
  float* o_t   = s_acc + BJK;                        // 65536 f32, [j][k][b]
  int*   flags = (int*)(o_t + BJK);                  // 64-f32 pad
  u16*   X_p   = (u16*)((float*)d_ws + 2*BJK + 64);  // 2048*1024 u16 (4 MB)
  u16*   W_p   = X_p + (size_t)N_*1024;              // 33.5M u16 (67 MB)
  float* c_buf = (float*)(W_p + WTOT);               // 2048*32*64 f32 (16.8 MB)
  float* part  = c_buf + (size_t)N_*J_*64;           // CH_*32*2048 f32 (8.4 MB)
  // total ~97 MB (ws is 512 MiB per harness fill evidence)

  const dim3 blk(256);
  const dim3 g_ac(CH_, J_);    // accum: 1024 blocks
  const dim3 g_lg(64,  J_);    // logits: 2048 blocks

  detect_zero<<<64, blk, 0, stream>>>((const u16*)X, (const u16*)Wm, flags, s_acc);
  pack_x<<<N_/4, blk, 0, stream>>>(X, flags, X_p);
  pack_w<<<WTOT/(256*16), blk, 0, stream>>>(Wm, flags, W_p);

  // iter 0: uniform c (1/32 folded into squash<0>)
  accum_kernel<0><<<g_ac, blk, 0, stream>>>(X_p, W_p, nullptr, part);
  reduce_kernel<<<J_, blk, 0, stream>>>(part, s_acc);
  squash_kernel<0><<<8, blk, 0, stream>>>(s_acc, o_t, flags, nullptr);

  // iters 1,2
  logits_kernel<<<g_lg, blk, 0, stream>>>(X_p, W_p, o_t, c_buf);
  softmax_kernel<<<N_/4, blk, 0, stream>>>(c_buf);
  accum_kernel<1><<<g_ac, blk, 0, stream>>>(X_p, W_p, c_buf, part);
  reduce_kernel<<<J_, blk, 0, stream>>>(part, s_acc);
  squash_kernel<1><<<8, blk, 0, stream>>>(s_acc, o_t, flags, nullptr);

  logits_kernel<<<g_lg, blk, 0, stream>>>(X_p, W_p, o_t, c_buf);
  softmax_kernel<<<N_/4, blk, 0, stream>>>(c_buf);
  accum_kernel<1><<<g_ac, blk, 0, stream>>>(X_p, W_p, c_buf, part);
  reduce_kernel<<<J_, blk, 0, stream>>>(part, s_acc);
  squash_kernel<2><<<8, blk, 0, stream>>>(s_acc, o_t, flags, d_out);
}